// Round 12
// baseline (318.784 us; speedup 1.0000x reference)
//
#include <hip/hip_runtime.h>
#include <hip/hip_bf16.h>

// N=262144 sentences (uniform 16/bag, contiguous), D=768, C=53
// Y = X*W^T via bf16 MFMA. R12: producer/consumer, bag-complete phases.
// Phase = 1 bag = 16 rows x 768 cols = 48KB CONTIGUOUS global read.
//   waves 4-7 (producers): stage x -> LDS bf16, loads issued 1 phase ahead
//   waves 0-3 (consumers): n-tile w, full K (24 MFMA), att+softmax+logits
#define DIM   768
#define NC    53
#define NCP   64
#define MTB   256      // rows per block = 16 bags
#define NTH   512      // 8 waves
#define NPH   16       // phases (bags) per block
#define LSTR  776      // LDS row stride in bf16 elems (1552 B)
#define LBUF  (16 * LSTR)

typedef __attribute__((ext_vector_type(8))) short short8;
typedef __attribute__((ext_vector_type(4))) float f32x4;

static __device__ inline unsigned short f2bf(float f) {
    unsigned u = __float_as_uint(f);
    u += 0x7fff + ((u >> 16) & 1);           // RNE
    return (unsigned short)(u >> 16);
}

// ---- kernel 1: W fp32 [53][768] -> bf16 [64][768] in d_ws ----
__global__ void wconv_kernel(const float* __restrict__ W, unsigned short* __restrict__ Wt) {
    const int idx = blockIdx.x * 256 + threadIdx.x;
    if (idx >= NCP * DIM) return;
    const int c = idx / DIM, k = idx - c * DIM;
    Wt[idx] = f2bf((c < NC) ? W[c * DIM + k] : 0.f);
}

// 4 fp32 -> 4 bf16 (8 B) via packed cvt
static __device__ inline void cvt_store8(unsigned short* dst, const float4 v) {
    union { __hip_bfloat162 h[2]; uint2 u; } z;
    z.h[0] = __float22bfloat162_rn(make_float2(v.x, v.y));
    z.h[1] = __float22bfloat162_rn(make_float2(v.z, v.w));
    *reinterpret_cast<uint2*>(dst) = z.u;
}

__global__ __launch_bounds__(NTH) void bag_attn_pc(
    const float* __restrict__ x,              // [N][768] fp32
    const unsigned short* __restrict__ Wt,    // [64][768] bf16 (d_ws)
    const float* __restrict__ bias,           // [53]
    const int*   __restrict__ query,          // [N]
    float*       __restrict__ out)            // [B][53]
{
    __shared__ __align__(16) unsigned short Ab[2][LBUF];   // 48.5 KiB
    __shared__ float att_sm[2][16];
    __shared__ int   qbuf[MTB];

    const int t   = threadIdx.x;
    const int w   = t >> 6;
    const int l   = t & 63;
    const int r16 = l & 15;
    const int kq  = l >> 4;
    const int blk = blockIdx.x;
    const int row_g = blk * MTB;

    if (t < MTB) qbuf[t] = query[row_g + t];

    const bool prod = (w >= 4);
    const int  pid  = w - 4;

    // producer state: 12 chunks of 1KB per phase; chunk c -> row c/3,
    // k-third c%3; lane l reads 16B at col-offset (c%3)*256 + l*4 fp32.
    const float* xb = x + (size_t)row_g * DIM;
    float4 rg[12];
    int    lofs[12];
    if (prod) {
        #pragma unroll
        for (int j = 0; j < 12; ++j) {
            const int c = pid * 12 + j;
            lofs[j] = (c / 3) * LSTR + (c % 3) * 256 + l * 4;
        }
        // prologue: load+store phase 0; issue loads for phase 1
        #pragma unroll
        for (int j = 0; j < 12; ++j) {
            const int c = pid * 12 + j;
            rg[j] = *reinterpret_cast<const float4*>(
                xb + (size_t)(c / 3) * DIM + (c % 3) * 256 + l * 4);
        }
        #pragma unroll
        for (int j = 0; j < 12; ++j)
            cvt_store8(&Ab[0][lofs[j]], rg[j]);
        #pragma unroll
        for (int j = 0; j < 12; ++j) {
            const int c = pid * 12 + j;
            rg[j] = *reinterpret_cast<const float4*>(
                xb + (size_t)(16 + c / 3) * DIM + (c % 3) * 256 + l * 4);
        }
    }
    const unsigned short* wb = Wt + (size_t)(16 * w + r16) * DIM + kq * 8;

    __syncthreads();

    for (int p = 0; p < NPH; ++p) {
        f32x4 acc = (f32x4){0.f, 0.f, 0.f, 0.f};
        if (prod) {
            // store phase p+1 (loads issued one full phase ago), then
            // issue loads for phase p+2 (stay in flight across this phase)
            if (p + 1 < NPH) {
                #pragma unroll
                for (int j = 0; j < 12; ++j)
                    cvt_store8(&Ab[(p + 1) & 1][lofs[j]], rg[j]);
            }
            if (p + 2 < NPH) {
                #pragma unroll
                for (int j = 0; j < 12; ++j) {
                    const int c = pid * 12 + j;
                    rg[j] = *reinterpret_cast<const float4*>(
                        xb + (size_t)((p + 2) * 16 + c / 3) * DIM
                           + (c % 3) * 256 + l * 4);
                }
            }
        } else {
            // consumer: n-tile w, bag p, full K from LDS + L2-hot Wt
            const unsigned short* ab = &Ab[p & 1][r16 * LSTR + kq * 8];
            #pragma unroll
            for (int kk = 0; kk < 24; ++kk) {
                const short8 a = *reinterpret_cast<const short8*>(ab + kk * 32);
                const short8 b = *reinterpret_cast<const short8*>(wb + kk * 32);
                acc = __builtin_amdgcn_mfma_f32_16x16x32_bf16(a, b, acc, 0, 0, 0);
            }
            // att extraction (D-layout: col=lane&15, row=kq*4+r)
            #pragma unroll
            for (int r = 0; r < 4; ++r) {
                const int s = kq * 4 + r;
                const int q = qbuf[p * 16 + s];
                if ((q >> 4) == w && (q & 15) == r16)
                    att_sm[p & 1][s] = acc[r];
            }
        }
        __syncthreads();
        if (!prod) {
            // softmax over the bag's 16 scores + weighted logits
            const float4* a4 = reinterpret_cast<const float4*>(&att_sm[p & 1][0]);
            const float4 A0 = a4[0], A1 = a4[1], A2 = a4[2], A3 = a4[3];
            float mx = fmaxf(fmaxf(fmaxf(A0.x, A0.y), fmaxf(A0.z, A0.w)),
                      fmaxf(fmaxf(fmaxf(A1.x, A1.y), fmaxf(A1.z, A1.w)),
                      fmaxf(fmaxf(fmaxf(A2.x, A2.y), fmaxf(A2.z, A2.w)),
                            fmaxf(fmaxf(A3.x, A3.y), fmaxf(A3.z, A3.w)))));
            float zz = __expf(A0.x-mx)+__expf(A0.y-mx)+__expf(A0.z-mx)+__expf(A0.w-mx)
                     + __expf(A1.x-mx)+__expf(A1.y-mx)+__expf(A1.z-mx)+__expf(A1.w-mx)
                     + __expf(A2.x-mx)+__expf(A2.y-mx)+__expf(A2.z-mx)+__expf(A2.w-mx)
                     + __expf(A3.x-mx)+__expf(A3.y-mx)+__expf(A3.z-mx)+__expf(A3.w-mx);
            const float inv = 1.f / zz;
            float4 As = A0;
            if (kq == 1) As = A1;
            if (kq == 2) As = A2;
            if (kq == 3) As = A3;
            const float e0 = __expf(As.x - mx) * inv;
            const float e1 = __expf(As.y - mx) * inv;
            const float e2 = __expf(As.z - mx) * inv;
            const float e3 = __expf(As.w - mx) * inv;
            float pv = e0 * acc[0] + e1 * acc[1] + e2 * acc[2] + e3 * acc[3];
            pv += __shfl_xor(pv, 16, 64);     // sum the 4 kq row-groups
            pv += __shfl_xor(pv, 32, 64);
            if (l < 16) {
                const int c = 16 * w + l;
                if (c < NC)
                    out[(size_t)(blk * 16 + p) * NC + c] = pv + bias[c];
            }
        }
    }
}

extern "C" void kernel_launch(void* const* d_in, const int* in_sizes, int n_in,
                              void* d_out, int out_size, void* d_ws, size_t ws_size,
                              hipStream_t stream) {
    const float* x     = (const float*)d_in[0];   // [N][768]
    const float* W     = (const float*)d_in[1];   // [53][768]
    const float* bias  = (const float*)d_in[2];   // [53]
    const int*   query = (const int*)d_in[4];     // [N]
    float* out = (float*)d_out;                   // [B][53]

    unsigned short* Wt = (unsigned short*)d_ws;   // 64*768*2 = 96 KiB

    const int nrows = in_sizes[0] / DIM;          // 262144
    const int nblk  = nrows / MTB;                // 1024

    wconv_kernel<<<(NCP * DIM + 255) / 256, 256, 0, stream>>>(W, Wt);
    bag_attn_pc<<<nblk, NTH, 0, stream>>>(x, Wt, bias, query, out);
}

// Round 13
// 200.919 us; speedup vs baseline: 1.5866x; 1.5866x over previous
//
#include <hip/hip_runtime.h>
#include <hip/hip_bf16.h>

// N=262144 sentences (uniform 16/bag, contiguous), D=768, C=53
// Y = X*W^T via bf16 MFMA. R13: ZERO-BARRIER pipeline.
//  - R10's cache-line-complete staging map is wave-private (wave w stages
//    and consumes rows [32w,32w+32)) -> all __syncthreads() deleted, so the
//    barrier's vmcnt(0) drain never interrupts the x-stream.
//  - B-fragments double-buffered in registers (bP/bQ), preloaded one phase
//    ahead -> MFMA waits are counted vmcnt, never drain the x prefetch.
#define DIM    768
#define NC     53
#define NCP    64
#define MTB    256     // rows per block (16 bags)
#define NTH    512     // 8 waves
#define KSTEP  32
#define NSTEPS 24      // 768/32
#define APAD   40      // LDS row stride (bf16): 80B rows -> 2-way banks (free)
#define D4     (DIM/4)

typedef __attribute__((ext_vector_type(8))) short short8;
typedef __attribute__((ext_vector_type(4))) float f32x4;

static __device__ inline unsigned short f2bf(float f) {
    unsigned u = __float_as_uint(f);
    u += 0x7fff + ((u >> 16) & 1);           // RNE
    return (unsigned short)(u >> 16);
}

// ---- kernel 1: W fp32 [53][768] -> bf16 [64][768] in d_ws ----
__global__ void wconv_kernel(const float* __restrict__ W, unsigned short* __restrict__ Wt) {
    const int idx = blockIdx.x * 256 + threadIdx.x;
    if (idx >= NCP * DIM) return;
    const int c = idx / DIM, k = idx - c * DIM;
    Wt[idx] = f2bf((c < NC) ? W[c * DIM + k] : 0.f);
}

// 4 fp32 -> 4 bf16 (8 B) via packed cvt
static __device__ inline void cvt_store8(unsigned short* dst, const float4 v) {
    union { __hip_bfloat162 h[2]; uint2 u; } z;
    z.h[0] = __float22bfloat162_rn(make_float2(v.x, v.y));
    z.h[1] = __float22bfloat162_rn(make_float2(v.z, v.w));
    *reinterpret_cast<uint2*>(dst) = z.u;
}

__global__ __launch_bounds__(NTH, 4) void bag_attn_nobar(
    const float* __restrict__ x,              // [N][768] fp32
    const unsigned short* __restrict__ Wt,    // [64][768] bf16 (d_ws)
    const float* __restrict__ bias,           // [53]
    const int*   __restrict__ query,          // [N]
    float*       __restrict__ out)            // [B][53]
{
    __shared__ __align__(16) unsigned short Ab[2][MTB * APAD];  // 40 KiB
    __shared__ float att_sm[16][16];          // wave-private rows 2w,2w+1

    const int t   = threadIdx.x;
    const int w   = t >> 6;        // wave 0..7 -> rows 32w..32w+31 (bags 2w,2w+1)
    const int l   = t & 63;
    const int r16 = l & 15;
    const int kq  = l >> 4;
    const int blk = blockIdx.x;
    const int row_g = blk * MTB;

    // staging map (cache-line-complete, WAVE-PRIVATE): load i, lane l ->
    //   row = 32w + 8i + (l>>3), 16B at byte (l&7)*16 of the row's 128B chunk
    const float4* xp = reinterpret_cast<const float4*>(x)
                     + (size_t)(row_g + 32 * w + (l >> 3)) * D4 + (l & 7);
    const int lofs = (32 * w + (l >> 3)) * APAD + (l & 7) * 4;  // + i*8*APAD

    f32x4 acc[2][4];
    #pragma unroll
    for (int mi = 0; mi < 2; ++mi)
        #pragma unroll
        for (int ni = 0; ni < 4; ++ni)
            acc[mi][ni] = (f32x4){0.f, 0.f, 0.f, 0.f};

    const unsigned short* wbase = Wt + (size_t)r16 * DIM + kq * 8;

#define LOADB(B, kk)                                                     \
    _Pragma("unroll")                                                    \
    for (int ni = 0; ni < 4; ++ni)                                       \
        B[ni] = *reinterpret_cast<const short8*>(                        \
            wbase + (size_t)(16 * ni) * DIM + (kk) * KSTEP);

#define LOADX(R, kk)                                                     \
    _Pragma("unroll")                                                    \
    for (int i = 0; i < 4; ++i)                                          \
        R[i] = xp[(size_t)i * 8 * D4 + (kk) * 8];

#define STOREX(R, buf)                                                   \
    _Pragma("unroll")                                                    \
    for (int i = 0; i < 4; ++i)                                          \
        cvt_store8(&Ab[buf][lofs + i * 8 * APAD], R[i]);

#define COMPUTE(p, B)                                                    \
    {                                                                    \
        short8 afr[2];                                                   \
        _Pragma("unroll")                                                \
        for (int mi = 0; mi < 2; ++mi)                                   \
            afr[mi] = *reinterpret_cast<const short8*>(                  \
                &Ab[p][(32 * w + 16 * mi + r16) * APAD + kq * 8]);       \
        _Pragma("unroll")                                                \
        for (int mi = 0; mi < 2; ++mi)                                   \
            _Pragma("unroll")                                            \
            for (int ni = 0; ni < 4; ++ni)                               \
                acc[mi][ni] = __builtin_amdgcn_mfma_f32_16x16x32_bf16(   \
                    afr[mi], B[ni], acc[mi][ni], 0, 0, 0);               \
    }

    short8 bP[4], bQ[4];
    float4 rA[4], rB[4];

    // prologue: bfr(0) + x(0), x(1) in flight; stage x(0) -> buf0
    LOADB(bP, 0);
    LOADX(rA, 0);
    LOADX(rB, 1);
    STOREX(rA, 0);                 // waits only rA's vmcnt (counted)

    for (int kk = 0; kk < NSTEPS; kk += 2) {
        // even phase: compute tile kk (buf0, bP); prefetch bfr(kk+1), x(kk+2)
        LOADB(bQ, kk + 1);
        if (kk + 2 < NSTEPS) LOADX(rA, kk + 2);
        COMPUTE(0, bP);            // vmcnt counted: bP done, x-stream in flight
        STOREX(rB, 1);             // rB = x(kk+1), issued one phase ago
        // odd phase: compute tile kk+1 (buf1, bQ); prefetch bfr(kk+2), x(kk+3)
        if (kk + 2 < NSTEPS) LOADB(bP, kk + 2);
        if (kk + 3 < NSTEPS) LOADX(rB, kk + 3);
        COMPUTE(1, bQ);
        if (kk + 2 < NSTEPS) STOREX(rA, 0);
    }
#undef LOADB
#undef LOADX
#undef STOREX
#undef COMPUTE

    // ---- epilogue: att extraction (D-layout: col=lane&15, row=kq*4+reg) ----
    // query read directly from global (L2-hot, off critical path)
    #pragma unroll
    for (int mi = 0; mi < 2; ++mi) {
        #pragma unroll
        for (int r = 0; r < 4; ++r) {
            const int s_loc = (kq << 2) + r;
            const int q = query[row_g + 32 * w + 16 * mi + s_loc];
            if ((q & 15) == r16) {            // one lane per row matches
                float v = acc[mi][0][r];
                if ((q >> 4) == 1) v = acc[mi][1][r];
                if ((q >> 4) == 2) v = acc[mi][2][r];
                if ((q >> 4) == 3) v = acc[mi][3][r];
                att_sm[2 * w + mi][s_loc] = v;
            }
        }
    }
    // att_sm rows 2w,2w+1 written+read by wave w only -> no barrier

    #pragma unroll
    for (int mi = 0; mi < 2; ++mi) {
        const int bag = 2 * w + mi;
        const float4* a4 = reinterpret_cast<const float4*>(&att_sm[bag][0]);
        const float4 A0 = a4[0], A1 = a4[1], A2 = a4[2], A3 = a4[3];
        float mx = fmaxf(fmaxf(fmaxf(A0.x, A0.y), fmaxf(A0.z, A0.w)),
                  fmaxf(fmaxf(fmaxf(A1.x, A1.y), fmaxf(A1.z, A1.w)),
                  fmaxf(fmaxf(fmaxf(A2.x, A2.y), fmaxf(A2.z, A2.w)),
                        fmaxf(fmaxf(A3.x, A3.y), fmaxf(A3.z, A3.w)))));
        float zz = __expf(A0.x-mx)+__expf(A0.y-mx)+__expf(A0.z-mx)+__expf(A0.w-mx)
                 + __expf(A1.x-mx)+__expf(A1.y-mx)+__expf(A1.z-mx)+__expf(A1.w-mx)
                 + __expf(A2.x-mx)+__expf(A2.y-mx)+__expf(A2.z-mx)+__expf(A2.w-mx)
                 + __expf(A3.x-mx)+__expf(A3.y-mx)+__expf(A3.z-mx)+__expf(A3.w-mx);
        const float inv = 1.f / zz;
        float4 As = A0;
        if (kq == 1) As = A1;
        if (kq == 2) As = A2;
        if (kq == 3) As = A3;
        const float e0 = __expf(As.x - mx) * inv;
        const float e1 = __expf(As.y - mx) * inv;
        const float e2 = __expf(As.z - mx) * inv;
        const float e3 = __expf(As.w - mx) * inv;
        #pragma unroll
        for (int ni = 0; ni < 4; ++ni) {
            float p = e0 * acc[mi][ni][0] + e1 * acc[mi][ni][1]
                    + e2 * acc[mi][ni][2] + e3 * acc[mi][ni][3];
            p += __shfl_xor(p, 16, 64);       // sum the 4 kq row-groups
            p += __shfl_xor(p, 32, 64);
            if (l < 16) {
                const int c = 16 * ni + l;
                if (c < NC)
                    out[(size_t)(blk * 16 + bag) * NC + c] = p + bias[c];
            }
        }
    }
}

extern "C" void kernel_launch(void* const* d_in, const int* in_sizes, int n_in,
                              void* d_out, int out_size, void* d_ws, size_t ws_size,
                              hipStream_t stream) {
    const float* x     = (const float*)d_in[0];   // [N][768]
    const float* W     = (const float*)d_in[1];   // [53][768]
    const float* bias  = (const float*)d_in[2];   // [53]
    const int*   query = (const int*)d_in[4];     // [N]
    float* out = (float*)d_out;                   // [B][53]

    unsigned short* Wt = (unsigned short*)d_ws;   // 64*768*2 = 96 KiB

    const int nrows = in_sizes[0] / DIM;          // 262144
    const int nblk  = nrows / MTB;                // 1024

    wconv_kernel<<<(NCP * DIM + 255) / 256, 256, 0, stream>>>(W, Wt);
    bag_attn_nobar<<<nblk, NTH, 0, stream>>>(x, Wt, bias, query, out);
}